// Round 6
// baseline (292.147 us; speedup 1.0000x reference)
//
#include <hip/hip_runtime.h>

typedef _Float16 half8 __attribute__((ext_vector_type(8)));
typedef float floatx4 __attribute__((ext_vector_type(4)));
typedef float f32x4 __attribute__((ext_vector_type(4)));
typedef unsigned int uint4v __attribute__((ext_vector_type(4)));

#define B_DIM 8
#define C_DIM 64
#define T_DIM 128
#define N_DIM 207
#define O_DIM 64
#define CSTR  (T_DIM * N_DIM)
#define NTW   13            // n-tile width (16 tiles x 13 = 208 >= 207)

// ---------------------------------------------------------------------------
// Kernel 0: pack Wq|Wk|Wv (fp32 [64 o][64 c]) -> fp16 in d_ws. [arr][o][c].
// ---------------------------------------------------------------------------
__global__ void pack_w(const float* __restrict__ Wq,
                       const float* __restrict__ Wk,
                       const float* __restrict__ Wv,
                       _Float16* __restrict__ ws)
{
    int i = threadIdx.x + blockIdx.x * blockDim.x;
    const int per = O_DIM * C_DIM;          // 4096
    for (int m = i; m < 3 * per; m += blockDim.x * gridDim.x) {
        int arr = m / per, rem = m % per;
        const float* W = (arr == 0) ? Wq : (arr == 1) ? Wk : Wv;
        ws[m] = (_Float16)W[rem];
    }
}

// ---------------------------------------------------------------------------
// Main: fully-unrolled t-marching MFMA kernel (round-4 step machinery).
// ROUND-6 change: pure TLP fix. n re-tiled 13-wide -> grid 16x8x8 = 1024
// blocks = exactly 4.0 blocks/CU (no straggler pass); launch_bounds(256,4);
// LDS stays 36KB so 4 blocks/CU are resident (147KB < 160KB). MFMA columns
// nq=13..15 are clamped duplicates, masked at store (no double writes).
// Everything else (GLDS staging, 3 buffers, 2-ahead vmcnt table, XCD
// swizzle batch-per-XCD, circular windows) is round-4-verified.
// ---------------------------------------------------------------------------

#define GLDS(gp_, lp_)                                                       \
    __builtin_amdgcn_global_load_lds(                                        \
        (const __attribute__((address_space(1))) void*)(gp_),                \
        (__attribute__((address_space(3))) void*)(lp_), 4, 0, 0)

// stage one t-row (q,k,v) into buffer P_: 12 global_load_lds per wave
#define STAGE(tg_, P_)                                                       \
    {                                                                        \
        const int tcl_  = min(max((tg_), 0), T_DIM - 1);                     \
        const int toff_ = tcl_ * N_DIM;                                      \
        _Pragma("unroll")                                                    \
        for (int arr_ = 0; arr_ < 3; ++arr_) {                               \
            const float* ab_ = (arr_ == 0) ? qb2 : (arr_ == 1) ? kb2 : vb2;  \
            _Pragma("unroll")                                                \
            for (int i_ = 0; i_ < 4; ++i_) {                                 \
                GLDS(ab_ + toff_ + col_off[i_],                              \
                     &xls[P_][arr_][wv * 4 + i_][0][0]);                     \
            }                                                                \
        }                                                                    \
    }

// build f16 MFMA B-fragment (8 c-values for lane column nq) from f32 LDS
#define MKFRAG(P_, arr_, kk_, dst_)                                          \
    {                                                                        \
        const float* ch_ = &xls[P_][arr_][qd * 2 + (kk_) * 8][nq][0];        \
        f32x4 A_ = *(const f32x4*)(ch_);                                     \
        f32x4 B_ = *(const f32x4*)(ch_ + 64);                                \
        uint4v t_;                                                           \
        t_[0] = __builtin_bit_cast(unsigned int, __builtin_amdgcn_cvt_pkrtz(A_[0], A_[1])); \
        t_[1] = __builtin_bit_cast(unsigned int, __builtin_amdgcn_cvt_pkrtz(A_[2], A_[3])); \
        t_[2] = __builtin_bit_cast(unsigned int, __builtin_amdgcn_cvt_pkrtz(B_[0], B_[1])); \
        t_[3] = __builtin_bit_cast(unsigned int, __builtin_amdgcn_cvt_pkrtz(B_[2], B_[3])); \
        dst_ = __builtin_bit_cast(half8, t_);                                \
    }

#define MFMA16(a_, b_, c_) __builtin_amdgcn_mfma_f32_16x16x32_f16(a_, b_, c_, 0, 0, 0)

#define VMWAIT(N_) asm volatile("s_waitcnt vmcnt(" #N_ ")" ::: "memory")

// one t-step, r_ and N_ are LITERAL constants.
// vmcnt keep-suffix at step r: loads row r+1 (12, if r<=20) + stores from
// steps r-1, r-2 (4 each, if those steps >= 6). Rows staged 2 ahead.
#define STEP(r_, N_)                                                         \
    {                                                                        \
        __builtin_amdgcn_sched_barrier(0);                                   \
        VMWAIT(N_);                                                          \
        __builtin_amdgcn_s_barrier();                                        \
        __builtin_amdgcn_sched_barrier(0);                                   \
        if ((r_) <= 19) STAGE(t0 - 1 + (r_), ((r_) + 2) % 3)                 \
        __builtin_amdgcn_sched_barrier(0);                                   \
        half8 fk0, fk1, fv0, fv1;                                            \
        MKFRAG((r_) % 3, 1, 0, fk0)  MKFRAG((r_) % 3, 1, 1, fk1)             \
        MKFRAG((r_) % 3, 2, 0, fv0)  MKFRAG((r_) % 3, 2, 1, fv1)             \
        floatx4 aq = {0.f, 0.f, 0.f, 0.f};                                   \
        floatx4 ak = {0.f, 0.f, 0.f, 0.f};                                   \
        floatx4 av = {0.f, 0.f, 0.f, 0.f};                                   \
        ak = MFMA16(af[1][0], fk0, ak);  ak = MFMA16(af[1][1], fk1, ak);     \
        av = MFMA16(af[2][0], fv0, av);  av = MFMA16(af[2][1], fv1, av);     \
        if ((r_) >= 3 && (r_) <= 18) {                                       \
            half8 fq0, fq1;                                                  \
            MKFRAG((r_) % 3, 0, 0, fq0)  MKFRAG((r_) % 3, 0, 1, fq1)         \
            aq = MFMA16(af[0][0], fq0, aq);  aq = MFMA16(af[0][1], fq1, aq); \
        }                                                                    \
        const int  tg_   = t0 - 3 + (r_);                                    \
        const bool rowv_ = (tg_ >= 0) && (tg_ < T_DIM);                      \
        _Pragma("unroll")                                                    \
        for (int j = 0; j < 4; ++j) {                                        \
            Kw[j][(r_) % 7]  = rowv_ ? (ak[j] + bk_r[j]) : 0.f;              \
            Vw[j][(r_) % 7]  = rowv_ ? (av[j] + bv_r[j]) : 0.f;              \
            Qd4[j][(r_) % 4] = aq[j] + bq_r[j];                              \
        }                                                                    \
        if ((r_) >= 6) {                                                     \
            const int to_ = t0 + (r_) - 6;                                   \
            const int n_g = n0 + nq;                                         \
            if (nq < NTW && n_g < N_DIM) {                                   \
                _Pragma("unroll")                                            \
                for (int j = 0; j < 4; ++j) {                                \
                    const float qv = Qd4[j][((r_) + 1) % 4] * 1.44269504f;   \
                    float s[7];                                              \
                    _Pragma("unroll")                                        \
                    for (int i = 0; i < 7; ++i)                              \
                        s[i] = qv * Kw[j][((r_) + 1 + i) % 7];               \
                    float mx = s[0];                                         \
                    _Pragma("unroll")                                        \
                    for (int i = 1; i < 7; ++i) mx = fmaxf(mx, s[i]);        \
                    float den = 0.f, num = 0.f;                              \
                    _Pragma("unroll")                                        \
                    for (int i = 0; i < 7; ++i) {                            \
                        float e = exp2f(s[i] - mx);                          \
                        den += e;                                            \
                        num = fmaf(e, Vw[j][((r_) + 1 + i) % 7], num);       \
                    }                                                        \
                    out[((size_t)(b * O_DIM + o0 + qd * 4 + j) * T_DIM + to_) * N_DIM + n_g] \
                        = num * __builtin_amdgcn_rcpf(den);                  \
                }                                                            \
            }                                                                \
        }                                                                    \
    }

__global__ __launch_bounds__(256, 4)
void attn_mfma(const float* __restrict__ q,
               const float* __restrict__ k,
               const float* __restrict__ v,
               const float* __restrict__ bq,
               const float* __restrict__ bk,
               const float* __restrict__ bv,
               const _Float16* __restrict__ wpk,
               float* __restrict__ out)
{
    // f32 staging: [buf][arr][cb][n][cw] = 3*3*16*16*4*4B = 36864 B
    __shared__ __align__(16) float xls[3][3][16][16][4];

    const int tid  = threadIdx.x;
    const int lane = tid & 63;
    const int wv   = tid >> 6;        // wave = o-slice, also staging cb-group
    const int nq   = lane & 15;       // D col (n), A row (m)
    const int qd   = lane >> 4;       // quad

    // bijective XCD swizzle: 1024 blocks = 8 XCDs x 128; XCD x owns batch x,
    // nb fastest within -> straddle/halo L2 sharing (round-4 verified).
    const int bid = (int)blockIdx.x + 16 * ((int)blockIdx.y + 8 * (int)blockIdx.z);
    const int swz = (bid & 7) * 128 + (bid >> 3);
    const int nb  = swz & 15;         // 0..15 (13 n each)
    const int tc  = (swz >> 4) & 7;   // 0..7  (16 t each)
    const int b   = swz >> 7;         // 0..7

    const int t0 = tc * 16;
    const int o0 = wv * 16;
    const int n0 = nb * NTW;

    // ---- staging lane mapping: lane -> (n = lane>>2, cw = lane&3) ----
    const int cl   = lane & 3;
    const int nrow = lane >> 2;
    const int n_cl = min(n0 + nrow, N_DIM - 1);
    int col_off[4];
    #pragma unroll
    for (int i = 0; i < 4; ++i)
        col_off[i] = ((wv * 4 + i) * 4 + cl) * CSTR + n_cl;

    const float* qb2 = q + (size_t)b * C_DIM * CSTR;
    const float* kb2 = k + (size_t)b * C_DIM * CSTR;
    const float* vb2 = v + (size_t)b * C_DIM * CSTR;

    // ---- loop-invariant A-fragments: W[o0+m][k], m=nq, k=qd*8+j+kk*32 ----
    half8 af[3][2];
    #pragma unroll
    for (int arr = 0; arr < 3; ++arr)
        #pragma unroll
        for (int kk = 0; kk < 2; ++kk)
            af[arr][kk] = *(const half8*)(wpk + ((size_t)(arr * 64 + o0 + nq) * 64
                                                 + qd * 8 + kk * 32));

    // ---- bias per lane-reg: D row o_l = qd*4+reg ----
    float bq_r[4], bk_r[4], bv_r[4];
    #pragma unroll
    for (int j = 0; j < 4; ++j) {
        const int og = o0 + qd * 4 + j;
        bq_r[j] = bq[og]; bk_r[j] = bk[og]; bv_r[j] = bv[og];
    }

    // ---- circular windows (literal indices after unroll) ----
    float Kw[4][7], Vw[4][7], Qd4[4][4];
    #pragma unroll
    for (int j = 0; j < 4; ++j) {
        #pragma unroll
        for (int i = 0; i < 7; ++i) { Kw[j][i] = 0.f; Vw[j][i] = 0.f; }
        #pragma unroll
        for (int i = 0; i < 4; ++i) Qd4[j][i] = 0.f;
    }

    // ---- prologue: stage rows 0,1 (2-ahead) ----
    STAGE(t0 - 3, 0)
    STAGE(t0 - 2, 1)

    // ---- 22 fully-unrolled steps; vmcnt table per keep-suffix math ----
    STEP( 0, 12)  STEP( 1, 12)  STEP( 2, 12)  STEP( 3, 12)
    STEP( 4, 12)  STEP( 5, 12)  STEP( 6, 12)  STEP( 7, 16)
    STEP( 8, 20)  STEP( 9, 20)  STEP(10, 20)  STEP(11, 20)
    STEP(12, 20)  STEP(13, 20)  STEP(14, 20)  STEP(15, 20)
    STEP(16, 20)  STEP(17, 20)  STEP(18, 20)  STEP(19, 20)
    STEP(20, 20)  STEP(21,  8)
}

extern "C" void kernel_launch(void* const* d_in, const int* in_sizes, int n_in,
                              void* d_out, int out_size, void* d_ws, size_t ws_size,
                              hipStream_t stream)
{
    const float* q  = (const float*)d_in[0];
    const float* k  = (const float*)d_in[1];
    const float* v  = (const float*)d_in[2];
    const float* Wq = (const float*)d_in[3];
    const float* bq = (const float*)d_in[4];
    const float* Wk = (const float*)d_in[5];
    const float* bk = (const float*)d_in[6];
    const float* Wv = (const float*)d_in[7];
    const float* bv = (const float*)d_in[8];
    float* o = (float*)d_out;

    _Float16* ws_h = (_Float16*)d_ws;   // 24 KB used

    hipLaunchKernelGGL(pack_w, dim3(3), dim3(256), 0, stream, Wq, Wk, Wv, ws_h);

    dim3 grid(16, 8, B_DIM);            // (n-tile13, t-chunk, b) = 1024 blocks
    dim3 block(256);
    hipLaunchKernelGGL(attn_mfma, grid, block, 0, stream,
                       q, k, v, bq, bk, bv, (const _Float16*)ws_h, o);
}

// Round 7
// 254.600 us; speedup vs baseline: 1.1475x; 1.1475x over previous
//
#include <hip/hip_runtime.h>

typedef _Float16 half8 __attribute__((ext_vector_type(8)));
typedef float floatx4 __attribute__((ext_vector_type(4)));
typedef unsigned int uint4v __attribute__((ext_vector_type(4)));

#define B_DIM 8
#define C_DIM 64
#define T_DIM 128
#define N_DIM 207
#define O_DIM 64
#define CSTR  (T_DIM * N_DIM)

// ---------------------------------------------------------------------------
// Kernel 0: pack Wq|Wk|Wv (fp32 [64 o][64 c]) -> fp16 in d_ws. [arr][o][c].
// ---------------------------------------------------------------------------
__global__ void pack_w(const float* __restrict__ Wq,
                       const float* __restrict__ Wk,
                       const float* __restrict__ Wv,
                       _Float16* __restrict__ ws)
{
    int i = threadIdx.x + blockIdx.x * blockDim.x;
    const int per = O_DIM * C_DIM;          // 4096
    for (int m = i; m < 3 * per; m += blockDim.x * gridDim.x) {
        int arr = m / per, rem = m % per;
        const float* W = (arr == 0) ? Wq : (arr == 1) ? Wk : Wv;
        ws[m] = (_Float16)W[rem];
    }
}

// ---------------------------------------------------------------------------
// Main: r4 structure + WIDE staging (global_load_lds width=16).
//  * Staging: 3 dwordx4 GLDS per wave per row (was 12 dword) -> 4x fewer
//    VMEM instructions, same segments/bytes. LDS chunk (cs,q) holds
//    (c = CG(cs), n-quad q) where CG is a bijective c-shuffle chosen so
//    fragment reads are 2-way-max bank aliased (free, m136).
//  * Fragment gather: 8x ds_read_b32 per frag, single per-lane base VGPR
//    (ladd) + compile-time immediate offsets -> zero per-step LDS addr VALU.
//  * Edge tile nb==12: dword fallback (same layout, per-lane n clamp) --
//    avoids a 4B OOB read past the exactly-page-sized tensors.
//  * Everything else is round-4-verified: 3 LDS buffers (36KB), 2-ahead
//    prefetch + exact per-step vmcnt keep-suffix, full 22-step unroll,
//    circular windows, XCD swizzle (batch-per-XCD).
// CG mapping: cs bits -> c: j=(cs>>1)&7, qd=(cs&1)+2*((cs>>4)&1), kk=cs>>5,
//             c = kk*32 + qd*8 + j.  (inverse used by the reader's ladd)
// ---------------------------------------------------------------------------

#define GLDS16(gp_, lp_)                                                     \
    __builtin_amdgcn_global_load_lds(                                        \
        (const __attribute__((address_space(1))) void*)(gp_),                \
        (__attribute__((address_space(3))) void*)(lp_), 16, 0, 0)

#define GLDS4(gp_, lp_)                                                      \
    __builtin_amdgcn_global_load_lds(                                        \
        (const __attribute__((address_space(1))) void*)(gp_),                \
        (__attribute__((address_space(3))) void*)(lp_), 4, 0, 0)

// stage one t-row (q,k,v) into buffer P_.
// main path: 1 dwordx4 GLDS per array per wave (wave wv owns chunks
// wv*64..wv*64+63 = 1KB, dest = uniform base + lane*16 per m104).
// nb==12 path: 4 dword GLDS per array per wave, identical layout, clamped n.
#define STAGE(tg_, P_)                                                       \
    {                                                                        \
        const int tcl_  = min(max((tg_), 0), T_DIM - 1);                     \
        const int toff_ = tcl_ * N_DIM;                                      \
        if (nb != 12) {                                                      \
            _Pragma("unroll")                                                \
            for (int arr_ = 0; arr_ < 3; ++arr_) {                           \
                const float* ab_ = (arr_ == 0) ? qb2 : (arr_ == 1) ? kb2 : vb2; \
                GLDS16(ab_ + toff_ + cof16, &xls[P_][arr_][wv * 256]);       \
            }                                                                \
        } else {                                                             \
            _Pragma("unroll")                                                \
            for (int arr_ = 0; arr_ < 3; ++arr_) {                           \
                const float* ab_ = (arr_ == 0) ? qb2 : (arr_ == 1) ? kb2 : vb2; \
                _Pragma("unroll")                                            \
                for (int s_ = 0; s_ < 4; ++s_)                               \
                    GLDS4(ab_ + toff_ + cofd[s_],                            \
                          &xls[P_][arr_][wv * 256 + s_ * 64]);               \
            }                                                                \
        }                                                                    \
    }

#define PKU(a_, b_) __builtin_bit_cast(unsigned int, __builtin_amdgcn_cvt_pkrtz((a_), (b_)))

// build f16 MFMA B-fragment (c = qd*8+kk*32+{0..7} at column n=nq) from the
// chunk-permuted LDS. All offsets compile-time; base = lrd (per-lane VGPR).
#define MKFRAG32(P_, arr_, kk_, dst_)                                        \
    {                                                                        \
        const float* p_ = lrd + ((P_) * 3072 + (arr_) * 1024 + (kk_) * 512); \
        uint4v t_;                                                           \
        t_[0] = PKU(p_[0],   p_[32]);                                        \
        t_[1] = PKU(p_[64],  p_[96]);                                        \
        t_[2] = PKU(p_[128], p_[160]);                                       \
        t_[3] = PKU(p_[192], p_[224]);                                       \
        dst_ = __builtin_bit_cast(half8, t_);                                \
    }

#define MFMA16(a_, b_, c_) __builtin_amdgcn_mfma_f32_16x16x32_f16(a_, b_, c_, 0, 0, 0)

#define VMWAIT(N_) asm volatile("s_waitcnt vmcnt(" #N_ ")" ::: "memory")

// one t-step; r_, N16_, N4_ are LITERAL constants.
// per-wave queue keep-suffix at step r (L loads/row): stores_{r-2} + L + stores_{r-1}
//   L=3 : r0-6:3, r7:7, r8-20:11, r21:8
//   L=12: r0-6:12, r7:16, r8-20:20, r21:8   (r4-verified table)
#define STEP(r_, N16_, N4_)                                                  \
    {                                                                        \
        __builtin_amdgcn_sched_barrier(0);                                   \
        if (nb != 12) { VMWAIT(N16_); } else { VMWAIT(N4_); }                \
        __builtin_amdgcn_s_barrier();                                        \
        __builtin_amdgcn_sched_barrier(0);                                   \
        if ((r_) <= 19) STAGE(t0 - 1 + (r_), ((r_) + 2) % 3)                 \
        __builtin_amdgcn_sched_barrier(0);                                   \
        half8 fk0, fk1, fv0, fv1;                                            \
        MKFRAG32((r_) % 3, 1, 0, fk0)  MKFRAG32((r_) % 3, 1, 1, fk1)         \
        MKFRAG32((r_) % 3, 2, 0, fv0)  MKFRAG32((r_) % 3, 2, 1, fv1)         \
        floatx4 aq = {0.f, 0.f, 0.f, 0.f};                                   \
        floatx4 ak = {0.f, 0.f, 0.f, 0.f};                                   \
        floatx4 av = {0.f, 0.f, 0.f, 0.f};                                   \
        ak = MFMA16(af[1][0], fk0, ak);  ak = MFMA16(af[1][1], fk1, ak);     \
        av = MFMA16(af[2][0], fv0, av);  av = MFMA16(af[2][1], fv1, av);     \
        if ((r_) >= 3 && (r_) <= 18) {                                       \
            half8 fq0, fq1;                                                  \
            MKFRAG32((r_) % 3, 0, 0, fq0)  MKFRAG32((r_) % 3, 0, 1, fq1)     \
            aq = MFMA16(af[0][0], fq0, aq);  aq = MFMA16(af[0][1], fq1, aq); \
        }                                                                    \
        const int  tg_   = t0 - 3 + (r_);                                    \
        const bool rowv_ = (tg_ >= 0) && (tg_ < T_DIM);                      \
        _Pragma("unroll")                                                    \
        for (int j = 0; j < 4; ++j) {                                        \
            Kw[j][(r_) % 7]  = rowv_ ? (ak[j] + bk_r[j]) : 0.f;              \
            Vw[j][(r_) % 7]  = rowv_ ? (av[j] + bv_r[j]) : 0.f;              \
            Qd4[j][(r_) % 4] = aq[j] + bq_r[j];                              \
        }                                                                    \
        if ((r_) >= 6) {                                                     \
            const int to_ = t0 + (r_) - 6;                                   \
            const int n_g = n0 + nq;                                         \
            if (n_g < N_DIM) {                                               \
                _Pragma("unroll")                                            \
                for (int j = 0; j < 4; ++j) {                                \
                    const float qv = Qd4[j][((r_) + 1) % 4] * 1.44269504f;   \
                    float s[7];                                              \
                    _Pragma("unroll")                                        \
                    for (int i = 0; i < 7; ++i)                              \
                        s[i] = qv * Kw[j][((r_) + 1 + i) % 7];               \
                    float mx = s[0];                                         \
                    _Pragma("unroll")                                        \
                    for (int i = 1; i < 7; ++i) mx = fmaxf(mx, s[i]);        \
                    float den = 0.f, num = 0.f;                              \
                    _Pragma("unroll")                                        \
                    for (int i = 0; i < 7; ++i) {                            \
                        float e = exp2f(s[i] - mx);                          \
                        den += e;                                            \
                        num = fmaf(e, Vw[j][((r_) + 1 + i) % 7], num);       \
                    }                                                        \
                    out[((size_t)(b * O_DIM + o0 + qd * 4 + j) * T_DIM + to_) * N_DIM + n_g] \
                        = num * __builtin_amdgcn_rcpf(den);                  \
                }                                                            \
            }                                                                \
        }                                                                    \
    }

__global__ __launch_bounds__(256, 3)
void attn_mfma(const float* __restrict__ q,
               const float* __restrict__ k,
               const float* __restrict__ v,
               const float* __restrict__ bq,
               const float* __restrict__ bk,
               const float* __restrict__ bv,
               const _Float16* __restrict__ wpk,
               float* __restrict__ out)
{
    // staging: [buf][arr][1024 f32] = 3*3*4KB = 36864 B; chunk-permuted c.
    __shared__ __align__(16) float xls[3][3][1024];

    const int tid  = threadIdx.x;
    const int lane = tid & 63;
    const int wv   = tid >> 6;        // wave = o-slice, also staging chunk-group
    const int nq   = lane & 15;       // D col (n), A row (m)
    const int qd   = lane >> 4;       // quad

    // bijective XCD swizzle: 832 blocks = 8 XCDs x 104; XCD x owns batch x,
    // nb fastest within -> straddle/halo L2 sharing (round-4 verified).
    const int bid = (int)blockIdx.x + 13 * ((int)blockIdx.y + 8 * (int)blockIdx.z);
    const int swz = (bid & 7) * 104 + (bid >> 3);
    const int nb  = swz % 13;         // 0..12 (16 n each)
    const int tc  = (swz / 13) & 7;   // 0..7  (16 t each)
    const int b   = swz / 104;        // 0..7

    const int t0 = tc * 16;
    const int o0 = wv * 16;
    const int n0 = nb * 16;

    // ---- per-lane LDS read base for fragment gather (bytes/4 = words) ----
    // byte addr of (c,q,nl): cs(c)*64 + q*16 + nl*4, cs = inverse CG.
    // lane-invariant part: (qd&1)*64 + (qd>>1)*1024 + (nq>>2)*16 + (nq&3)*4
    const int ladd = (qd & 1) * 64 + (qd >> 1) * 1024 + (nq >> 2) * 16 + (nq & 3) * 4;
    const float* lrd = (const float*)&xls[0][0][0] + (ladd >> 2);

    // ---- staging address precompute ----
    // main (dwordx4): lane l -> chunk wv*64+l: cs = wv*16+(l>>2), n-quad l&3
    const int cs16 = wv * 16 + (lane >> 2);
    const int cg16 = ((cs16 >> 5) << 5)
                   + (((cs16 & 1) + ((cs16 >> 4) & 1) * 2) << 3)
                   + ((cs16 >> 1) & 7);
    const int cof16 = cg16 * CSTR + n0 + (lane & 3) * 4;
    // fallback (dword, nb==12): sub-instr s -> chunk wv*64+s*16+(l>>2)
    int cofd[4];
    #pragma unroll
    for (int s = 0; s < 4; ++s) {
        const int cs = wv * 16 + s * 4 + (lane >> 4);
        const int cg = ((cs >> 5) << 5)
                     + (((cs & 1) + ((cs >> 4) & 1) * 2) << 3)
                     + ((cs >> 1) & 7);
        const int nn = min(n0 + ((lane >> 2) & 3) * 4 + (lane & 3), N_DIM - 1);
        cofd[s] = cg * CSTR + nn;
    }

    const float* qb2 = q + (size_t)b * C_DIM * CSTR;
    const float* kb2 = k + (size_t)b * C_DIM * CSTR;
    const float* vb2 = v + (size_t)b * C_DIM * CSTR;

    // ---- loop-invariant A-fragments: W[o0+m][k], m=nq, k=qd*8+j+kk*32 ----
    half8 af[3][2];
    #pragma unroll
    for (int arr = 0; arr < 3; ++arr)
        #pragma unroll
        for (int kk = 0; kk < 2; ++kk)
            af[arr][kk] = *(const half8*)(wpk + ((size_t)(arr * 64 + o0 + nq) * 64
                                                 + qd * 8 + kk * 32));

    // ---- bias per lane-reg: D row o_l = qd*4+reg ----
    float bq_r[4], bk_r[4], bv_r[4];
    #pragma unroll
    for (int j = 0; j < 4; ++j) {
        const int og = o0 + qd * 4 + j;
        bq_r[j] = bq[og]; bk_r[j] = bk[og]; bv_r[j] = bv[og];
    }

    // ---- circular windows (literal indices after unroll) ----
    float Kw[4][7], Vw[4][7], Qd4[4][4];
    #pragma unroll
    for (int j = 0; j < 4; ++j) {
        #pragma unroll
        for (int i = 0; i < 7; ++i) { Kw[j][i] = 0.f; Vw[j][i] = 0.f; }
        #pragma unroll
        for (int i = 0; i < 4; ++i) Qd4[j][i] = 0.f;
    }

    // ---- prologue: stage rows 0,1 (2-ahead) ----
    STAGE(t0 - 3, 0)
    STAGE(t0 - 2, 1)

    // ---- 22 fully-unrolled steps; vmcnt tables per staging path ----
    STEP( 0,  3, 12)  STEP( 1,  3, 12)  STEP( 2,  3, 12)  STEP( 3,  3, 12)
    STEP( 4,  3, 12)  STEP( 5,  3, 12)  STEP( 6,  3, 12)  STEP( 7,  7, 16)
    STEP( 8, 11, 20)  STEP( 9, 11, 20)  STEP(10, 11, 20)  STEP(11, 11, 20)
    STEP(12, 11, 20)  STEP(13, 11, 20)  STEP(14, 11, 20)  STEP(15, 11, 20)
    STEP(16, 11, 20)  STEP(17, 11, 20)  STEP(18, 11, 20)  STEP(19, 11, 20)
    STEP(20, 11, 20)  STEP(21,  8,  8)
}

extern "C" void kernel_launch(void* const* d_in, const int* in_sizes, int n_in,
                              void* d_out, int out_size, void* d_ws, size_t ws_size,
                              hipStream_t stream)
{
    const float* q  = (const float*)d_in[0];
    const float* k  = (const float*)d_in[1];
    const float* v  = (const float*)d_in[2];
    const float* Wq = (const float*)d_in[3];
    const float* bq = (const float*)d_in[4];
    const float* Wk = (const float*)d_in[5];
    const float* bk = (const float*)d_in[6];
    const float* Wv = (const float*)d_in[7];
    const float* bv = (const float*)d_in[8];
    float* o = (float*)d_out;

    _Float16* ws_h = (_Float16*)d_ws;   // 24 KB used

    hipLaunchKernelGGL(pack_w, dim3(3), dim3(256), 0, stream, Wq, Wk, Wv, ws_h);

    dim3 grid(13, 8, B_DIM);            // (n-tile, t-chunk, b) = 832 blocks
    dim3 block(256);
    hipLaunchKernelGGL(attn_mfma, grid, block, 0, stream,
                       q, k, v, bq, bk, bv, (const _Float16*)ws_h, o);
}